// Round 1
// baseline (196.970 us; speedup 1.0000x reference)
//
#include <hip/hip_runtime.h>
#include <cstdint>
#include <cstddef>

#define NUM_HEADS 16
#define HEAD_DIM  64
#define WINDOW    512
#define D_MODEL   1024
#define BATCH     2
#define SEQ       2048
#define MTOT      (BATCH*SEQ)   // 4096
#define NQKV      (3*D_MODEL)   // 3072

typedef short bf16x8 __attribute__((ext_vector_type(8)));
typedef float f32x4  __attribute__((ext_vector_type(4)));

__device__ __forceinline__ f32x4 mfma16(bf16x8 a, bf16x8 b, f32x4 c) {
  return __builtin_amdgcn_mfma_f32_16x16x32_bf16(a, b, c, 0, 0, 0);
}

// fp32 -> bf16 round-to-nearest-even (values are well-behaved, no NaN path needed)
__device__ __forceinline__ unsigned short f2bf(float f) {
  unsigned int u = __float_as_uint(f);
  u += 0x7fffu + ((u >> 16) & 1u);
  return (unsigned short)(u >> 16);
}
__device__ __forceinline__ float bf2f(unsigned short b) {
  return __uint_as_float(((unsigned int)b) << 16);
}

// async global->LDS, 16B per lane. LDS dest = wave-uniform base + lane*16 (m104 caveat):
// our call sites all use lds = base + t*8 ushorts, which satisfies it.
__device__ __forceinline__ void gld16(const unsigned short* g, unsigned short* l) {
  __builtin_amdgcn_global_load_lds(
      (const __attribute__((address_space(1))) unsigned int*)g,
      (__attribute__((address_space(3))) unsigned int*)l, 16, 0, 0);
}

// ---------------- elementwise fp32 -> bf16 ----------------
__global__ __launch_bounds__(256) void cvt_bf16_kernel(const float* __restrict__ in,
                                                       unsigned short* __restrict__ out) {
  int i = (blockIdx.x * 256 + threadIdx.x) * 4;
  float4 v = *(const float4*)(in + i);
  ushort4 o;
  o.x = f2bf(v.x); o.y = f2bf(v.y); o.z = f2bf(v.z); o.w = f2bf(v.w);
  *(ushort4*)(out + i) = o;
}

// ---------------- transpose + convert: in fp32 (R,C) -> out bf16 (C,R) ----------------
__global__ __launch_bounds__(256) void transpose_cvt_kernel(const float* __restrict__ in,
                                                            unsigned short* __restrict__ out,
                                                            int R, int C) {
  __shared__ float tile[32][33];
  int tx = threadIdx.x, ty = threadIdx.y;          // (32, 8)
  int c0 = blockIdx.x * 32, r0 = blockIdx.y * 32;  // R, C are multiples of 32
#pragma unroll
  for (int i = 0; i < 32; i += 8)
    tile[ty + i][tx] = in[(size_t)(r0 + ty + i) * C + c0 + tx];
  __syncthreads();
#pragma unroll
  for (int i = 0; i < 32; i += 8)
    out[(size_t)(c0 + ty + i) * R + r0 + tx] = f2bf(tile[tx][ty + i]);
}

// ---------------- m97-style 128x128 bf16 GEMM mainloop (A row-major, B^T row-major) -------
__device__ __forceinline__ void gemm_mainloop(const unsigned short* __restrict__ A,
                                              const unsigned short* __restrict__ Bt,
                                              int K, int m0, int n0,
                                              unsigned short* sA, unsigned short* sB,
                                              f32x4 (&acc)[4][4]) {
  const int t = threadIdx.x;
  const int lane = t & 63, wave = t >> 6;
  const int wm = wave >> 1, wn = wave & 1;
  const int lhi = lane >> 4, llo = lane & 15;
  f32x4 zero = {0.f, 0.f, 0.f, 0.f};
#pragma unroll
  for (int i = 0; i < 4; ++i)
#pragma unroll
    for (int j = 0; j < 4; ++j) acc[i][j] = zero;

  const unsigned short* gA = A  + (size_t)(m0 + (t >> 2)) * K + ((t & 3) << 3);
  const unsigned short* gB = Bt + (size_t)(n0 + (t >> 2)) * K + ((t & 3) << 3);
  const size_t rowskip = (size_t)64 * K;
  unsigned short* lA = sA + t * 8;
  unsigned short* lB = sB + t * 8;
  const unsigned short* rA = sA + (wm * 64 + llo) * 32 + lhi * 8;
  const unsigned short* rB = sB + (wn * 64 + llo) * 32 + lhi * 8;

  for (int k0 = 0; k0 < K; k0 += 32) {
    gld16(gA, lA); gld16(gA + rowskip, lA + 2048);
    gld16(gB, lB); gld16(gB + rowskip, lB + 2048);
    gA += 32; gB += 32;
    __syncthreads();
    bf16x8 af[4], bfr[4];
#pragma unroll
    for (int i = 0; i < 4; ++i) af[i]  = *(const bf16x8*)(rA + i * 512);
#pragma unroll
    for (int i = 0; i < 4; ++i) bfr[i] = *(const bf16x8*)(rB + i * 512);
#pragma unroll
    for (int i = 0; i < 4; ++i)
#pragma unroll
      for (int j = 0; j < 4; ++j)
        acc[i][j] = mfma16(af[i], bfr[j], acc[i][j]);
    __syncthreads();
  }
}

// ---------------- QKV projection GEMM, epilogue scatters Q(prescaled), K, V^T ------------
__global__ __launch_bounds__(256) void qkv_gemm_kernel(const unsigned short* __restrict__ Xb,
                                                       const unsigned short* __restrict__ Wt,
                                                       const float* __restrict__ bias,
                                                       unsigned short* __restrict__ Qw,
                                                       unsigned short* __restrict__ Kw,
                                                       unsigned short* __restrict__ Vtw) {
  __shared__ __align__(16) unsigned short sA[128 * 32];
  __shared__ __align__(16) unsigned short sB[128 * 32];
  f32x4 acc[4][4];
  const int m0 = blockIdx.y * 128, n0 = blockIdx.x * 128;
  gemm_mainloop(Xb, Wt, D_MODEL, m0, n0, sA, sB, acc);

  const int t = threadIdx.x, lane = t & 63, wave = t >> 6;
  const int wm = wave >> 1, wn = wave & 1, lhi = lane >> 4, llo = lane & 15;
#pragma unroll
  for (int ti = 0; ti < 4; ++ti) {
#pragma unroll
    for (int tj = 0; tj < 4; ++tj) {
      int n = n0 + wn * 64 + tj * 16 + llo;
      float bv = bias[n];
      int c = n >> 10, h = (n >> 6) & 15, d = n & 63;
#pragma unroll
      for (int r = 0; r < 4; ++r) {
        int m = m0 + wm * 64 + ti * 16 + lhi * 4 + r;
        int b = m >> 11, s = m & 2047;
        int bh = b * 16 + h;
        float v = acc[ti][tj][r] + bv;
        if (c == 0)      Qw[((size_t)(bh * 2048 + s)) * 64 + d]  = f2bf(v * 0.125f);
        else if (c == 1) Kw[((size_t)(bh * 2048 + s)) * 64 + d]  = f2bf(v);
        else             Vtw[((size_t)(bh * 64 + d)) * 2048 + s] = f2bf(v);
      }
    }
  }
}

// ---------------- flash sliding-window attention -----------------------------------------
// block = (q-tile of 64, bh); 4 waves x 16 q-rows each.
__global__ __launch_bounds__(256) void attn_kernel(const unsigned short* __restrict__ Qw,
                                                   const unsigned short* __restrict__ Kw,
                                                   const unsigned short* __restrict__ Vtw,
                                                   unsigned short* __restrict__ AO) {
  __shared__ __align__(16) unsigned short sK[64 * 64];      // (key,d) row-major
  __shared__ __align__(16) unsigned short sV[64 * 64];      // (d,key) row-major (V^T)
  __shared__ __align__(16) unsigned short sP[4][16 * 72];   // per-wave P, stride 72 (144B)
  const int t = threadIdx.x, lane = t & 63, wave = t >> 6;
  const int lhi = lane >> 4, llo = lane & 15;
  const int q0 = blockIdx.x * 64;
  const int bh = blockIdx.y;
  const unsigned short* Qb = Qw  + (size_t)bh * 2048 * 64;
  const unsigned short* Kb = Kw  + (size_t)bh * 2048 * 64;
  const unsigned short* Vb = Vtw + (size_t)bh * 64 * 2048;

  const int qrow = q0 + wave * 16 + llo;  // A-operand row for this lane
  bf16x8 qf0 = *(const bf16x8*)(Qb + (size_t)qrow * 64 + lhi * 8);
  bf16x8 qf1 = *(const bf16x8*)(Qb + (size_t)qrow * 64 + 32 + lhi * 8);

  float m_i[4], l_i[4];
  f32x4 o[4];
  f32x4 zero = {0.f, 0.f, 0.f, 0.f};
#pragma unroll
  for (int r = 0; r < 4; ++r) { m_i[r] = -1e30f; l_i[r] = 0.f; }
#pragma unroll
  for (int j = 0; j < 4; ++j) o[j] = zero;

  const int kt_lo = (q0 > 511) ? ((q0 - 511) >> 6) : 0;
  const int kt_hi = q0 >> 6;
  for (int kt = kt_lo; kt <= kt_hi; ++kt) {
    const int k0 = kt << 6;
    // stage K tile (contiguous 8KB) and V^T tile (64 rows x 128B)
    gld16(Kb + (size_t)k0 * 64 + t * 8, sK + t * 8);
    gld16(Kb + (size_t)k0 * 64 + 2048 + t * 8, sK + 2048 + t * 8);
    gld16(Vb + (size_t)(t >> 3) * 2048 + k0 + (t & 7) * 8, sV + t * 8);
    gld16(Vb + (size_t)((t >> 3) + 32) * 2048 + k0 + (t & 7) * 8, sV + 2048 + t * 8);
    __syncthreads();

    // S = Q K^T  (scale pre-folded into Q)
    f32x4 sc[4];
#pragma unroll
    for (int tj = 0; tj < 4; ++tj) {
      bf16x8 kf0 = *(const bf16x8*)(sK + (tj * 16 + llo) * 64 + lhi * 8);
      bf16x8 kf1 = *(const bf16x8*)(sK + (tj * 16 + llo) * 64 + 32 + lhi * 8);
      f32x4 z = zero;
      z = mfma16(qf0, kf0, z);
      z = mfma16(qf1, kf1, z);
      sc[tj] = z;
    }

    // mask + online softmax (C-layout: row = lhi*4+r, col = llo)
#pragma unroll
    for (int r = 0; r < 4; ++r) {
      const int qr = q0 + wave * 16 + lhi * 4 + r;
      float sv[4];
      float mx = -1e30f;
#pragma unroll
      for (int tj = 0; tj < 4; ++tj) {
        int key = k0 + tj * 16 + llo;
        float s = sc[tj][r];
        bool ok = (key <= qr) && (qr - key < WINDOW);
        s = ok ? s : -1e30f;
        sv[tj] = s;
        mx = fmaxf(mx, s);
      }
#pragma unroll
      for (int off = 1; off < 16; off <<= 1) mx = fmaxf(mx, __shfl_xor(mx, off));
      float mn = fmaxf(m_i[r], mx);
      float a  = __expf(m_i[r] - mn);
      float rs = 0.f;
#pragma unroll
      for (int tj = 0; tj < 4; ++tj) {
        float p = __expf(sv[tj] - mn);
        unsigned short pb = f2bf(p);
        sP[wave][(lhi * 4 + r) * 72 + tj * 16 + llo] = pb;
        rs += bf2f(pb);  // normalize with the weights actually used
      }
#pragma unroll
      for (int off = 1; off < 16; off <<= 1) rs += __shfl_xor(rs, off);
      l_i[r] = l_i[r] * a + rs;
      m_i[r] = mn;
#pragma unroll
      for (int tj = 0; tj < 4; ++tj) o[tj][r] *= a;
    }

    // O += P V   (A-frag of P from per-wave LDS region; same-wave ds ordering suffices)
    bf16x8 pf0 = *(const bf16x8*)(&sP[wave][llo * 72 + lhi * 8]);
    bf16x8 pf1 = *(const bf16x8*)(&sP[wave][llo * 72 + 32 + lhi * 8]);
#pragma unroll
    for (int tj = 0; tj < 4; ++tj) {
      bf16x8 vf0 = *(const bf16x8*)(sV + (tj * 16 + llo) * 64 + lhi * 8);
      bf16x8 vf1 = *(const bf16x8*)(sV + (tj * 16 + llo) * 64 + 32 + lhi * 8);
      o[tj] = mfma16(pf1, vf1, mfma16(pf0, vf0, o[tj]));
    }
    __syncthreads();
  }

  const int b = bh >> 4, h = bh & 15;
#pragma unroll
  for (int tj = 0; tj < 4; ++tj)
#pragma unroll
    for (int r = 0; r < 4; ++r) {
      int qr = q0 + wave * 16 + lhi * 4 + r;
      float v = o[tj][r] / l_i[r];
      AO[(size_t)(b * 2048 + qr) * 1024 + h * 64 + tj * 16 + llo] = f2bf(v);
    }
}

// ---------------- output projection GEMM -------------------------------------------------
__global__ __launch_bounds__(256) void out_gemm_kernel(const unsigned short* __restrict__ AO,
                                                       const unsigned short* __restrict__ Wt,
                                                       const float* __restrict__ bias,
                                                       float* __restrict__ out) {
  __shared__ __align__(16) unsigned short sA[128 * 32];
  __shared__ __align__(16) unsigned short sB[128 * 32];
  f32x4 acc[4][4];
  const int m0 = blockIdx.y * 128, n0 = blockIdx.x * 128;
  gemm_mainloop(AO, Wt, D_MODEL, m0, n0, sA, sB, acc);

  const int t = threadIdx.x, lane = t & 63, wave = t >> 6;
  const int wm = wave >> 1, wn = wave & 1, lhi = lane >> 4, llo = lane & 15;
#pragma unroll
  for (int ti = 0; ti < 4; ++ti)
#pragma unroll
    for (int tj = 0; tj < 4; ++tj) {
      int n = n0 + wn * 64 + tj * 16 + llo;
      float bv = bias[n];
#pragma unroll
      for (int r = 0; r < 4; ++r) {
        int m = m0 + wm * 64 + ti * 16 + lhi * 4 + r;
        out[(size_t)m * D_MODEL + n] = acc[ti][tj][r] + bv;
      }
    }
}

extern "C" void kernel_launch(void* const* d_in, const int* in_sizes, int n_in,
                              void* d_out, int out_size, void* d_ws, size_t ws_size,
                              hipStream_t stream) {
  const float* x      = (const float*)d_in[0];
  const float* qkv_w  = (const float*)d_in[1];
  const float* qkv_b  = (const float*)d_in[2];
  const float* out_w  = (const float*)d_in[3];
  const float* out_b  = (const float*)d_in[4];
  float* out = (float*)d_out;
  char* ws = (char*)d_ws;

  // workspace layout (48 MB total)
  unsigned short* Xb  = (unsigned short*)(ws);                          // 8 MB  x bf16
  unsigned short* Wq  = (unsigned short*)(ws + ((size_t)8  << 20));     // 6 MB  qkv_w^T bf16
  unsigned short* Wo  = (unsigned short*)(ws + ((size_t)14 << 20));     // 2 MB  out_w^T bf16
  unsigned short* Qw  = (unsigned short*)(ws + ((size_t)16 << 20));     // 8 MB  Q (bh,s,d) * 1/8
  unsigned short* Kw  = (unsigned short*)(ws + ((size_t)24 << 20));     // 8 MB  K (bh,s,d)
  unsigned short* Vtw = (unsigned short*)(ws + ((size_t)32 << 20));     // 8 MB  V^T (bh,d,s)
  unsigned short* AO  = (unsigned short*)(ws + ((size_t)40 << 20));     // 8 MB  attn out (m, hd)

  // 1) x -> bf16
  cvt_bf16_kernel<<<MTOT * D_MODEL / 1024, 256, 0, stream>>>(x, Xb);
  // 2) weights -> bf16 transposed (B^T layout for MFMA B-fragments)
  transpose_cvt_kernel<<<dim3(NQKV / 32, D_MODEL / 32), dim3(32, 8), 0, stream>>>(qkv_w, Wq, D_MODEL, NQKV);
  transpose_cvt_kernel<<<dim3(D_MODEL / 32, D_MODEL / 32), dim3(32, 8), 0, stream>>>(out_w, Wo, D_MODEL, D_MODEL);
  // 3) QKV projection
  qkv_gemm_kernel<<<dim3(NQKV / 128, MTOT / 128), 256, 0, stream>>>(Xb, Wq, qkv_b, Qw, Kw, Vtw);
  // 4) sliding-window flash attention
  attn_kernel<<<dim3(SEQ / 64, BATCH * NUM_HEADS), 256, 0, stream>>>(Qw, Kw, Vtw, AO);
  // 5) output projection
  out_gemm_kernel<<<dim3(D_MODEL / 128, MTOT / 128), 256, 0, stream>>>(AO, Wo, out_b, out);
}

// Round 2
// 180.909 us; speedup vs baseline: 1.0888x; 1.0888x over previous
//
#include <hip/hip_runtime.h>
#include <cstdint>
#include <cstddef>

#define NUM_HEADS 16
#define HEAD_DIM  64
#define WINDOW    512
#define D_MODEL   1024
#define BATCH     2
#define SEQ       2048
#define MTOT      (BATCH*SEQ)   // 4096
#define NQKV      (3*D_MODEL)   // 3072

typedef short bf16x8 __attribute__((ext_vector_type(8)));
typedef float f32x4  __attribute__((ext_vector_type(4)));

__device__ __forceinline__ f32x4 mfma16(bf16x8 a, bf16x8 b, f32x4 c) {
  return __builtin_amdgcn_mfma_f32_16x16x32_bf16(a, b, c, 0, 0, 0);
}

__device__ __forceinline__ unsigned short f2bf(float f) {
  unsigned int u = __float_as_uint(f);
  u += 0x7fffu + ((u >> 16) & 1u);
  return (unsigned short)(u >> 16);
}
__device__ __forceinline__ float bf2f(unsigned short b) {
  return __uint_as_float(((unsigned int)b) << 16);
}

// async global->LDS, 16B/lane; LDS dest = wave-uniform base + lane*16 (m104).
__device__ __forceinline__ void gld16(const unsigned short* g, unsigned short* l) {
  __builtin_amdgcn_global_load_lds(
      (const __attribute__((address_space(1))) unsigned int*)g,
      (__attribute__((address_space(3))) unsigned int*)l, 16, 0, 0);
}

// ---------------- elementwise fp32 -> bf16 ----------------
__global__ __launch_bounds__(256) void cvt_bf16_kernel(const float* __restrict__ in,
                                                       unsigned short* __restrict__ out) {
  int i = (blockIdx.x * 256 + threadIdx.x) * 4;
  float4 v = *(const float4*)(in + i);
  ushort4 o;
  o.x = f2bf(v.x); o.y = f2bf(v.y); o.z = f2bf(v.z); o.w = f2bf(v.w);
  *(ushort4*)(out + i) = o;
}

// ---------------- transpose + convert: fp32 (R,C) -> bf16 (C,R) ----------------
__global__ __launch_bounds__(256) void transpose_cvt_kernel(const float* __restrict__ in,
                                                            unsigned short* __restrict__ out,
                                                            int R, int C) {
  __shared__ float tile[32][33];
  int tx = threadIdx.x, ty = threadIdx.y;          // (32, 8)
  int c0 = blockIdx.x * 32, r0 = blockIdx.y * 32;
#pragma unroll
  for (int i = 0; i < 32; i += 8)
    tile[ty + i][tx] = in[(size_t)(r0 + ty + i) * C + c0 + tx];
  __syncthreads();
#pragma unroll
  for (int i = 0; i < 32; i += 8)
    out[(size_t)(c0 + ty + i) * R + r0 + tx] = f2bf(tile[tx][ty + i]);
}

// ---------------- batched bf16 transpose: (bh, s, d) -> (bh, d, s) ----------------
__global__ __launch_bounds__(256) void transpose_v_kernel(const unsigned short* __restrict__ in,
                                                          unsigned short* __restrict__ out) {
  __shared__ unsigned short tile[32][34];
  int tx = threadIdx.x, ty = threadIdx.y;          // (32, 8)
  int s0 = blockIdx.x * 32, d0 = blockIdx.y * 32, bh = blockIdx.z;
  const unsigned short* ib = in + (size_t)bh * 2048 * 64;
  unsigned short* ob = out + (size_t)bh * 64 * 2048;
#pragma unroll
  for (int i = 0; i < 32; i += 8)
    tile[ty + i][tx] = ib[(size_t)(s0 + ty + i) * 64 + d0 + tx];
  __syncthreads();
#pragma unroll
  for (int i = 0; i < 32; i += 8)
    ob[(size_t)(d0 + ty + i) * 2048 + s0 + tx] = tile[tx][ty + i];
}

// ---------------- m97-style 128x128 bf16 GEMM mainloop, XOR-swizzled LDS -------
// A row-major (M,K), Bt row-major (N,K). LDS rows = 32 ushorts = 4 chunks of 16B;
// chunk stored at position c' = c ^ ((row>>1)&3) -> conflict-free b128 frag reads.
__device__ __forceinline__ void gemm_mainloop(const unsigned short* __restrict__ A,
                                              const unsigned short* __restrict__ Bt,
                                              int K, int m0, int n0,
                                              unsigned short* sA, unsigned short* sB,
                                              f32x4 (&acc)[4][4]) {
  const int t = threadIdx.x;
  const int lane = t & 63, wave = t >> 6;
  const int wm = wave >> 1, wn = wave & 1;
  const int lhi = lane >> 4, llo = lane & 15;
  f32x4 zero = {0.f, 0.f, 0.f, 0.f};
#pragma unroll
  for (int i = 0; i < 4; ++i)
#pragma unroll
    for (int j = 0; j < 4; ++j) acc[i][j] = zero;

  const int cswz = (((t & 3) ^ ((t >> 3) & 3)) << 3);   // swizzled k-chunk for staging
  const unsigned short* gA = A  + (size_t)(m0 + (t >> 2)) * K + cswz;
  const unsigned short* gB = Bt + (size_t)(n0 + (t >> 2)) * K + cswz;
  const size_t rowskip = (size_t)64 * K;
  unsigned short* lA = sA + t * 8;
  unsigned short* lB = sB + t * 8;
  const int rsw = (lhi ^ ((llo >> 1) & 3)) * 8;          // swizzled chunk for frag reads
  const unsigned short* rA = sA + (wm * 64 + llo) * 32 + rsw;
  const unsigned short* rB = sB + (wn * 64 + llo) * 32 + rsw;

  for (int k0 = 0; k0 < K; k0 += 32) {
    gld16(gA, lA); gld16(gA + rowskip, lA + 2048);
    gld16(gB, lB); gld16(gB + rowskip, lB + 2048);
    gA += 32; gB += 32;
    __syncthreads();
    bf16x8 af[4], bfr[4];
#pragma unroll
    for (int i = 0; i < 4; ++i) af[i]  = *(const bf16x8*)(rA + i * 512);
#pragma unroll
    for (int i = 0; i < 4; ++i) bfr[i] = *(const bf16x8*)(rB + i * 512);
#pragma unroll
    for (int i = 0; i < 4; ++i)
#pragma unroll
      for (int j = 0; j < 4; ++j)
        acc[i][j] = mfma16(af[i], bfr[j], acc[i][j]);
    __syncthreads();
  }
}

// ---------------- QKV projection GEMM; scatters Q(prescaled), K, V (all coalesced) ------
__global__ __launch_bounds__(256) void qkv_gemm_kernel(const unsigned short* __restrict__ Xb,
                                                       const unsigned short* __restrict__ Wt,
                                                       const float* __restrict__ bias,
                                                       unsigned short* __restrict__ Qw,
                                                       unsigned short* __restrict__ Kw,
                                                       unsigned short* __restrict__ Vtmp) {
  __shared__ __align__(16) unsigned short sA[128 * 32];
  __shared__ __align__(16) unsigned short sB[128 * 32];
  f32x4 acc[4][4];
  const int m0 = blockIdx.y * 128, n0 = blockIdx.x * 128;
  gemm_mainloop(Xb, Wt, D_MODEL, m0, n0, sA, sB, acc);

  const int t = threadIdx.x, lane = t & 63, wave = t >> 6;
  const int wm = wave >> 1, wn = wave & 1, lhi = lane >> 4, llo = lane & 15;
#pragma unroll
  for (int ti = 0; ti < 4; ++ti) {
#pragma unroll
    for (int tj = 0; tj < 4; ++tj) {
      int n = n0 + wn * 64 + tj * 16 + llo;
      float bv = bias[n];
      int c = n >> 10, h = (n >> 6) & 15, d = n & 63;
#pragma unroll
      for (int r = 0; r < 4; ++r) {
        int m = m0 + wm * 64 + ti * 16 + lhi * 4 + r;
        int b = m >> 11, s = m & 2047;
        int bh = b * 16 + h;
        float v = acc[ti][tj][r] + bv;
        size_t idx = ((size_t)(bh * 2048 + s)) * 64 + d;
        if (c == 0)      Qw[idx]   = f2bf(v * 0.125f);
        else if (c == 1) Kw[idx]   = f2bf(v);
        else             Vtmp[idx] = f2bf(v);   // contiguous; transposed by transpose_v
      }
    }
  }
}

// ---------------- flash sliding-window attention (S^T formulation) -----------------------
// grid (bh, q-rev). Per block: 64 queries (4 waves x 16), 64-key tiles.
// S^T = K Q^T via mfma(A=K-frag, B=Q^T-frag): C col = query (llo), row = key.
// -> softmax reduction = 2 shfls; P written as ds_write_b64 in (query,key) layout.
__global__ __launch_bounds__(256) void attn_kernel(const unsigned short* __restrict__ Qw,
                                                   const unsigned short* __restrict__ Kw,
                                                   const unsigned short* __restrict__ Vtw,
                                                   unsigned short* __restrict__ AO) {
  __shared__ __align__(16) unsigned short sK[64 * 64];     // (key,d), XOR-swizzled chunks
  __shared__ __align__(16) unsigned short sV[64 * 64];     // (d,key), XOR-swizzled chunks
  __shared__ __align__(16) unsigned short sP[4][16 * 72];  // per-wave P (query,key), pad 72
  const int t = threadIdx.x, lane = t & 63, wave = t >> 6;
  const int lhi = lane >> 4, llo = lane & 15;
  const int bh = blockIdx.x;                 // bh%8 -> XCD; all q-tiles of bh share L2
  const int q0 = (31 - blockIdx.y) << 6;     // heaviest q-tiles dispatch first
  const unsigned short* Qb = Qw  + (size_t)bh * 2048 * 64;
  const unsigned short* Kb = Kw  + (size_t)bh * 2048 * 64;
  const unsigned short* Vb = Vtw + (size_t)bh * 64 * 2048;

  const int qrow = q0 + wave * 16 + llo;     // this lane's query (column of S^T)
  bf16x8 qf0 = *(const bf16x8*)(Qb + (size_t)qrow * 64 + lhi * 8);
  bf16x8 qf1 = *(const bf16x8*)(Qb + (size_t)qrow * 64 + 32 + lhi * 8);

  // staging: slot t -> LDS chunk t; logical chunk c = (t&7) ^ ((t>>3)&7)
  const int srow = t >> 3;
  const int scol = ((t & 7) ^ (srow & 7)) * 8;
  // fragment read: row & 7 == llo & 7 -> chunk position (lhi ^ (llo&7)); +4 chunk = ^32B*? 
  const int cpos  = (lhi ^ (llo & 7)) * 8;   // ushort offset of chunk
  const int cposx = cpos ^ 32;               // chunk (c^4): (a^4)*8 == a*8 ^ 32

  float m_i = -1e30f, l_i = 0.f;
  f32x4 o[4];
  f32x4 zero = {0.f, 0.f, 0.f, 0.f};
#pragma unroll
  for (int td = 0; td < 4; ++td) o[td] = zero;

  const int kt_lo = (q0 > 511) ? ((q0 - 511) >> 6) : 0;
  const int kt_hi = q0 >> 6;
  for (int kt = kt_lo; kt <= kt_hi; ++kt) {
    const int k0 = kt << 6;
    gld16(Kb + (size_t)(k0 + srow) * 64 + scol,      sK + t * 8);
    gld16(Kb + (size_t)(k0 + srow + 32) * 64 + scol, sK + t * 8 + 2048);
    gld16(Vb + (size_t)srow * 2048 + k0 + scol,        sV + t * 8);
    gld16(Vb + (size_t)(srow + 32) * 2048 + k0 + scol, sV + t * 8 + 2048);
    __syncthreads();

    // S^T tiles: row = key (tk*16 + lhi*4 + r), col = query (llo)
    f32x4 st[4];
#pragma unroll
    for (int tk = 0; tk < 4; ++tk) {
      const unsigned short* kr = sK + (tk * 16 + llo) * 64;
      bf16x8 kf0 = *(const bf16x8*)(kr + cpos);
      bf16x8 kf1 = *(const bf16x8*)(kr + cposx);
      f32x4 z = zero;
      z = mfma16(kf0, qf0, z);
      z = mfma16(kf1, qf1, z);
      st[tk] = z;
    }

    // mask + in-lane max over 16 keys, then 2-shfl cross-quad reduce
    const int kb = k0 + lhi * 4;
    float mx = -1e30f;
#pragma unroll
    for (int tk = 0; tk < 4; ++tk)
#pragma unroll
      for (int r = 0; r < 4; ++r) {
        int key = kb + tk * 16 + r;
        bool ok = (key <= qrow) && (qrow - key < WINDOW);
        float s = ok ? st[tk][r] : -1e30f;
        st[tk][r] = s;
        mx = fmaxf(mx, s);
      }
    mx = fmaxf(mx, __shfl_xor(mx, 16));
    mx = fmaxf(mx, __shfl_xor(mx, 32));
    float mn = fmaxf(m_i, mx);
    float a  = __expf(m_i - mn);   // fully-masked first tile: a=1 now, wiped by a=0 later
    float rs = 0.f;
    unsigned short* pw = &sP[wave][llo * 72];
#pragma unroll
    for (int tk = 0; tk < 4; ++tk) {
      ushort4 pb;
      pb.x = f2bf(__expf(st[tk][0] - mn));
      pb.y = f2bf(__expf(st[tk][1] - mn));
      pb.z = f2bf(__expf(st[tk][2] - mn));
      pb.w = f2bf(__expf(st[tk][3] - mn));
      *(ushort4*)(pw + tk * 16 + lhi * 4) = pb;
      rs += bf2f(pb.x) + bf2f(pb.y) + bf2f(pb.z) + bf2f(pb.w);
    }
    rs += __shfl_xor(rs, 16);
    rs += __shfl_xor(rs, 32);
    l_i = l_i * a + rs;
    m_i = mn;

    // broadcast alpha to O-rows (O C-layout row = query lhi*4+r)
    float aR[4];
#pragma unroll
    for (int r = 0; r < 4; ++r) aR[r] = __shfl(a, lhi * 4 + r);
#pragma unroll
    for (int td = 0; td < 4; ++td)
#pragma unroll
      for (int r = 0; r < 4; ++r) o[td][r] *= aR[r];

    // O += P V : A-frag of P (contiguous b128 from padded sP), B-frag of V from sV
    bf16x8 pf0 = *(const bf16x8*)(pw + lhi * 8);
    bf16x8 pf1 = *(const bf16x8*)(pw + 32 + lhi * 8);
#pragma unroll
    for (int td = 0; td < 4; ++td) {
      const unsigned short* vr = sV + (td * 16 + llo) * 64;
      bf16x8 vf0 = *(const bf16x8*)(vr + cpos);
      bf16x8 vf1 = *(const bf16x8*)(vr + cposx);
      o[td] = mfma16(pf0, vf0, o[td]);
      o[td] = mfma16(pf1, vf1, o[td]);
    }
    __syncthreads();
  }

  float lR[4];
#pragma unroll
  for (int r = 0; r < 4; ++r) lR[r] = __shfl(l_i, lhi * 4 + r);
  const int b = bh >> 4, h = bh & 15;
#pragma unroll
  for (int td = 0; td < 4; ++td)
#pragma unroll
    for (int r = 0; r < 4; ++r) {
      int qr = q0 + wave * 16 + lhi * 4 + r;
      AO[(size_t)(b * 2048 + qr) * 1024 + h * 64 + td * 16 + llo] = f2bf(o[td][r] / lR[r]);
    }
}

// ---------------- output projection GEMM -------------------------------------------------
__global__ __launch_bounds__(256) void out_gemm_kernel(const unsigned short* __restrict__ AO,
                                                       const unsigned short* __restrict__ Wt,
                                                       const float* __restrict__ bias,
                                                       float* __restrict__ out) {
  __shared__ __align__(16) unsigned short sA[128 * 32];
  __shared__ __align__(16) unsigned short sB[128 * 32];
  f32x4 acc[4][4];
  const int m0 = blockIdx.y * 128, n0 = blockIdx.x * 128;
  gemm_mainloop(AO, Wt, D_MODEL, m0, n0, sA, sB, acc);

  const int t = threadIdx.x, lane = t & 63, wave = t >> 6;
  const int wm = wave >> 1, wn = wave & 1, lhi = lane >> 4, llo = lane & 15;
#pragma unroll
  for (int ti = 0; ti < 4; ++ti)
#pragma unroll
    for (int tj = 0; tj < 4; ++tj) {
      int n = n0 + wn * 64 + tj * 16 + llo;
      float bv = bias[n];
#pragma unroll
      for (int r = 0; r < 4; ++r) {
        int m = m0 + wm * 64 + ti * 16 + lhi * 4 + r;
        out[(size_t)m * D_MODEL + n] = acc[ti][tj][r] + bv;
      }
    }
}

extern "C" void kernel_launch(void* const* d_in, const int* in_sizes, int n_in,
                              void* d_out, int out_size, void* d_ws, size_t ws_size,
                              hipStream_t stream) {
  const float* x      = (const float*)d_in[0];
  const float* qkv_w  = (const float*)d_in[1];
  const float* qkv_b  = (const float*)d_in[2];
  const float* out_w  = (const float*)d_in[3];
  const float* out_b  = (const float*)d_in[4];
  float* out = (float*)d_out;
  char* ws = (char*)d_ws;

  // workspace layout (48 MB total)
  unsigned short* Xb  = (unsigned short*)(ws);                          // 8 MB  x bf16
  unsigned short* Wq  = (unsigned short*)(ws + ((size_t)8  << 20));     // 6 MB  qkv_w^T bf16
  unsigned short* Wo  = (unsigned short*)(ws + ((size_t)14 << 20));     // 2 MB  out_w^T bf16
  unsigned short* Qw  = (unsigned short*)(ws + ((size_t)16 << 20));     // 8 MB  Q (bh,s,d)*1/8
  unsigned short* Kw  = (unsigned short*)(ws + ((size_t)24 << 20));     // 8 MB  K (bh,s,d)
  unsigned short* Vtw = (unsigned short*)(ws + ((size_t)32 << 20));     // 8 MB  V^T (bh,d,s)
  unsigned short* AO  = (unsigned short*)(ws + ((size_t)40 << 20));     // 8 MB  Vtmp, then attn out

  unsigned short* Vtmp = AO;  // V staged here; consumed by transpose_v before attn writes AO

  cvt_bf16_kernel<<<MTOT * D_MODEL / 1024, 256, 0, stream>>>(x, Xb);
  transpose_cvt_kernel<<<dim3(NQKV / 32, D_MODEL / 32), dim3(32, 8), 0, stream>>>(qkv_w, Wq, D_MODEL, NQKV);
  transpose_cvt_kernel<<<dim3(D_MODEL / 32, D_MODEL / 32), dim3(32, 8), 0, stream>>>(out_w, Wo, D_MODEL, D_MODEL);
  qkv_gemm_kernel<<<dim3(NQKV / 128, MTOT / 128), 256, 0, stream>>>(Xb, Wq, qkv_b, Qw, Kw, Vtmp);
  transpose_v_kernel<<<dim3(SEQ / 32, HEAD_DIM / 32, BATCH * NUM_HEADS), dim3(32, 8), 0, stream>>>(Vtmp, Vtw);
  attn_kernel<<<dim3(BATCH * NUM_HEADS, SEQ / 64), 256, 0, stream>>>(Qw, Kw, Vtw, AO);
  out_gemm_kernel<<<dim3(D_MODEL / 128, MTOT / 128), 256, 0, stream>>>(AO, Wo, out_b, out);
}